// Round 1
// baseline (509.523 us; speedup 1.0000x reference)
//
#include <hip/hip_runtime.h>
#include <hip/hip_bf16.h>

// Problem constants (from reference): B=16, N=4096 -> NTOK=65536, DIM=1024, T=8, E=64
#define NTOK  65536
#define DIM_  1024
#define NHEAD 8
#define EOUT  64
#define KBLK  32          // DIM_/32 k-steps of the 16x16x32 MFMA

typedef __bf16 bf16x8 __attribute__((ext_vector_type(8)));
typedef float  f32x4  __attribute__((ext_vector_type(4)));
typedef unsigned short u16x8 __attribute__((ext_vector_type(8)));

__device__ inline __bf16 cvt_bf16(float f) {
    __hip_bfloat16 h = __float2bfloat16(f);
    return __builtin_bit_cast(__bf16, h);
}

// ---------------------------------------------------------------------------
// Kernel 0: pack W [T, DIM, E] fp32 -> bf16 in exact MFMA B-fragment order.
// Wp flat index: (((t*KBLK + kb)*4 + et)*64 + lane)*8 + j
//   holds W[t][kb*32 + (lane>>4)*8 + j][et*16 + (lane&15)]
// ---------------------------------------------------------------------------
__global__ void pack_w(const float* __restrict__ W, unsigned short* __restrict__ Wp) {
    int x = blockIdx.x * blockDim.x + threadIdx.x;   // 8*32*4*64*8 = 524288 threads
    int j  = x & 7;
    int l  = (x >> 3) & 63;
    int et = (x >> 9) & 3;
    int kb = (x >> 11) & 31;
    int t  = x >> 16;
    int k = kb * 32 + (l >> 4) * 8 + j;
    int e = et * 16 + (l & 15);
    float v = W[((size_t)t * DIM_ + k) * EOUT + e];
    __hip_bfloat16 h = __float2bfloat16(v);
    Wp[x] = __builtin_bit_cast(unsigned short, h);
}

// ---------------------------------------------------------------------------
// Kernel 1: bucket tokens by head. Ballot-aggregated atomics: one atomicAdd
// per (wave, head) instead of per token.
// ---------------------------------------------------------------------------
__global__ void bucket_kernel(const int* __restrict__ idx,
                              int* __restrict__ cnt, int* __restrict__ list) {
    int i    = blockIdx.x * blockDim.x + threadIdx.x;   // exactly NTOK threads
    int lane = threadIdx.x & 63;
    int t = idx[i];
    #pragma unroll
    for (int h = 0; h < NHEAD; ++h) {
        unsigned long long m = __ballot(t == h);
        if (m) {
            int leader = __ffsll(m) - 1;
            int base = 0;
            if (lane == leader) base = atomicAdd(&cnt[h], __popcll(m));
            base = __shfl(base, leader, 64);
            if (t == h) {
                int rank = __popcll(m & ((1ull << lane) - 1ull));
                list[h * NTOK + base + rank] = i;
            }
        }
    }
}

// ---------------------------------------------------------------------------
// Kernel 2: gathered GEMM. Block = 256 threads = 4 waves; each wave computes a
// 16-token x 64-output tile for one head. A rows gathered from emb (fp32,
// cvt->bf16 in regs); B fragments are contiguous 16B loads from L2-resident Wp.
// ---------------------------------------------------------------------------
__global__ __launch_bounds__(256) void readout_gemm(
    const float* __restrict__ emb, const float* __restrict__ bias,
    const int* __restrict__ cnt, const int* __restrict__ list,
    const unsigned short* __restrict__ Wp, float* __restrict__ out)
{
    int head  = blockIdx.x & 7;
    int tile  = blockIdx.x >> 3;
    int count = cnt[head];
    int wave  = threadIdx.x >> 6;
    int lane  = threadIdx.x & 63;
    int mbase = tile * 64 + wave * 16;
    if (mbase >= count) return;

    int quad = lane >> 4, l16 = lane & 15;
    const int* mylist = list + head * NTOK;

    // A row for this lane (rows beyond count clamp to last valid; stores masked)
    int am = mbase + l16;
    if (am > count - 1) am = count - 1;
    int arow = mylist[am];
    const float* aptr = emb + (size_t)arow * DIM_ + quad * 8;

    // B fragment base: head block = KBLK*4*64*8 = 65536 ushorts
    const u16x8* bptr = reinterpret_cast<const u16x8*>(Wp + (size_t)head * 65536) + lane;

    f32x4 acc[4] = {};

    for (int kb = 0; kb < KBLK; ++kb) {
        const float4* ap = reinterpret_cast<const float4*>(aptr + kb * 32);
        float4 f0 = ap[0];
        float4 f1 = ap[1];
        bf16x8 a;
        a[0] = cvt_bf16(f0.x); a[1] = cvt_bf16(f0.y);
        a[2] = cvt_bf16(f0.z); a[3] = cvt_bf16(f0.w);
        a[4] = cvt_bf16(f1.x); a[5] = cvt_bf16(f1.y);
        a[6] = cvt_bf16(f1.z); a[7] = cvt_bf16(f1.w);
        #pragma unroll
        for (int et = 0; et < 4; ++et) {
            bf16x8 b = __builtin_bit_cast(bf16x8, bptr[(kb * 4 + et) * 64]);
            acc[et] = __builtin_amdgcn_mfma_f32_16x16x32_bf16(a, b, acc[et], 0, 0, 0);
        }
    }

    // Epilogue: C layout col=lane&15, row=(lane>>4)*4+i. Scatter + bias.
    int tok[4];
    #pragma unroll
    for (int i = 0; i < 4; ++i) {
        int m = mbase + quad * 4 + i;
        tok[i] = (m < count) ? mylist[m] : -1;
    }
    #pragma unroll
    for (int et = 0; et < 4; ++et) {
        float bv = bias[head * EOUT + et * 16 + l16];
        #pragma unroll
        for (int i = 0; i < 4; ++i) {
            if (tok[i] >= 0)
                out[(size_t)tok[i] * EOUT + et * 16 + l16] = acc[et][i] + bv;
        }
    }
}

// ---------------------------------------------------------------------------
// ws layout: [0,32)   cnt (8 ints, zeroed each call)
//            [1024, 1024+2MB)          per-head token lists
//            [1024+2MB, 1024+2MB+1MB)  packed bf16 W fragments
// total ~3.01 MB
// ---------------------------------------------------------------------------
extern "C" void kernel_launch(void* const* d_in, const int* in_sizes, int n_in,
                              void* d_out, int out_size, void* d_ws, size_t ws_size,
                              hipStream_t stream) {
    const float* emb  = (const float*)d_in[0];
    const int*   idx  = (const int*)d_in[1];
    const float* W    = (const float*)d_in[2];
    const float* bias = (const float*)d_in[3];
    float* out = (float*)d_out;

    char* ws = (char*)d_ws;
    int* cnt  = (int*)ws;
    int* list = (int*)(ws + 1024);
    unsigned short* Wp = (unsigned short*)(ws + 1024 + (size_t)NHEAD * NTOK * sizeof(int));

    hipMemsetAsync(cnt, 0, NHEAD * sizeof(int), stream);
    pack_w<<<(NHEAD * KBLK * 4 * 64 * 8) / 256, 256, 0, stream>>>(W, Wp);
    bucket_kernel<<<NTOK / 256, 256, 0, stream>>>(idx, cnt, list);
    readout_gemm<<<NHEAD * (NTOK / 64), 256, 0, stream>>>(emb, bias, cnt, list, Wp, out);
}